// Round 23
// baseline (97.472 us; speedup 1.0000x reference)
//
#include <hip/hip_runtime.h>
#include <hip/hip_bf16.h>
#include <math.h>

#define NB 2
#define EIN 4500
#define EOUT 9000
#define EPS 1e-5f

typedef __attribute__((ext_vector_type(8))) short bf16x8;
typedef __attribute__((ext_vector_type(4))) float f32x4;

__device__ inline uint32_t bfr(float x) {
    uint32_t u = __float_as_uint(x);
    return (u + 0x7fffu + ((u >> 16) & 1u)) >> 16;
}
__device__ inline uint32_t pk2(float a, float b) {
    __hip_bfloat162 h = __float22bfloat162_rn(make_float2(a, b));   // v_cvt_pk_bf16_f32
    uint32_t u;
    __builtin_memcpy(&u, &h, 4);
    return u;
}
__device__ inline float bf2f(ushort u) { return __uint_as_float((uint32_t)u << 16); }

// ---------- W pack, DENSE k' = c*5 + f (R15 layout, unchanged):
// Wq[((og8*NSTEP + st)*64 + lane)*8 + f8]: o = og8*16 + (lane&15),
// k' = st*32 + (lane>>4)*8 + f8, (c, feat) = (k'/5, k'%5).
__device__ inline void wpack_frag(const float* __restrict__ W, ushort* __restrict__ Wq,
                                  int i, int CIN) {
    int lane = i & 63; int t = i >> 6;
    int NSTEP = CIN * 5 / 32;
    int st = t % NSTEP, og = t / NSTEP;
    int o = og * 16 + (lane & 15);
    int k0 = st * 32 + (lane >> 4) * 8;
    uint32_t u[4];
#pragma unroll
    for (int q = 0; q < 4; ++q) {
        int ka = k0 + 2 * q, kb = ka + 1;
        float va = W[((size_t)o * CIN + ka / 5) * 5 + ka % 5];
        float vb = W[((size_t)o * CIN + kb / 5) * 5 + kb % 5];
        u[q] = pk2(va, vb);
    }
    *reinterpret_cast<uint4*>(Wq + (size_t)i * 8) = make_uint4(u[0], u[1], u[2], u[3]);
}

// ---------- tiled transpose f32 [R][C] -> bf16 [C][R] (one 32x32 tile per call)
__device__ inline void transpose_bf_body(float (*tile)[33], const float* __restrict__ in,
                                         ushort* __restrict__ out, int R, int C,
                                         int id, int nbx, int nby, int tid) {
    int bxt = id % nbx; int rest = id / nbx;
    int by = rest % nby; int b = rest / nby;
    int c0 = bxt * 32, r0 = by * 32;
    const float* inb = in + (size_t)b * R * C;
    ushort* outb = out + (size_t)b * C * R;
    int tx = tid & 31, ty = tid >> 5;   // 32 x 8
#pragma unroll
    for (int i = 0; i < 4; ++i) {
        int r = r0 + ty + i * 8, c = c0 + tx;
        if (r < R && c < C) tile[ty + i * 8][tx] = inb[(size_t)r * C + c];
    }
    __syncthreads();
#pragma unroll
    for (int i = 0; i < 4; ++i) {
        int c = c0 + ty + i * 8, r = r0 + tx;
        if (r < R && c < C) outb[(size_t)c * R + r] = (ushort)bfr(tile[tx][ty + i * 8]);
    }
}

// ---------- phase0: parent probe + transposes + wpack + stats-zero (R14/R15 structure).
#define GUESS_B 71    // ceil(18000/256)
#define FU_B 2256     // 141 x 8 x 2
#define FD_B 2256     // 282 x 4 x 2
#define WP_B 200      // 51200 items / 256
#define INIT_B 1      // stats only (1024 floats)
__global__ __launch_bounds__(256) void phase0_kernel(
    const float* __restrict__ unroll, int* __restrict__ parent, float* __restrict__ pval,
    const float* __restrict__ from_up, ushort* __restrict__ FU,
    const float* __restrict__ from_down, ushort* __restrict__ FD,
    const float* __restrict__ W_up, ushort* __restrict__ Wq_up,
    const float* __restrict__ W1, ushort* __restrict__ Wq_1,
    const float* __restrict__ W2, ushort* __restrict__ Wq_2,
    float* __restrict__ stats) {
    __shared__ float tile[32][33];
    int bx = blockIdx.x, tid = threadIdx.x;
    if (bx < GUESS_B) {
        int i = bx * 256 + tid;          // i = b*EOUT + eo
        if (i < NB * EOUT) {
            int eo = i % EOUT;
            const float* mb = unroll + (size_t)(i / EOUT) * EIN * EOUT;
            int p = eo >> 1;
            float v = mb[(size_t)p * EOUT + eo];
            if (v == 0.f) {              // general 1-sparse fallback (never hit here)
                p = 0; v = 0.f;
                for (int ei = 0; ei < EIN; ++ei) {
                    float x = mb[(size_t)ei * EOUT + eo];
                    if (x != 0.f) { p = ei; v = x; break; }
                }
            }
            parent[i] = p;
            pval[i] = v;
        }
    } else if (bx < GUESS_B + FU_B) {
        transpose_bf_body(tile, from_up, FU, 256, EIN, bx - GUESS_B, 141, 8, tid);
    } else if (bx < GUESS_B + FU_B + FD_B) {
        transpose_bf_body(tile, from_down, FD, 128, EOUT, bx - (GUESS_B + FU_B), 282, 4, tid);
    } else if (bx < GUESS_B + FU_B + FD_B + WP_B) {
        int i = (bx - (GUESS_B + FU_B + FD_B)) * 256 + tid;
        if (i < 20480) wpack_frag(W_up, Wq_up, i, 256);              // 8og x 40st x 64
        else if (i < 40960) wpack_frag(W1, Wq_1, i - 20480, 256);
        else wpack_frag(W2, Wq_2, i - 40960, 128);                   // 8og x 20st x 64
    } else {
#pragma unroll
        for (int j = 0; j < 4; ++j) stats[j * 256 + tid] = 0.f;
    }
}

// ---------- X1 = relu(norm1(Y2)), materialized once. Y2 read is streaming (Y2 was
// NT-stored); X1 write stays CACHED (it's conv2's gather target).
__global__ void norm_kernel(const ushort* __restrict__ Y2, const float* __restrict__ stats1,
                            ushort* __restrict__ X1) {
    int i = blockIdx.x * 256 + threadIdx.x;      // uint4 index
    if (i >= NB * EOUT * 128 / 8) return;
    int c0 = (i * 8) & 127;
    int b = (i * 8) / (EOUT * 128);
    float invE = 1.0f / (float)EOUT;
    uint4 v = reinterpret_cast<const uint4*>(Y2)[i];
    uint32_t wds[4] = {v.x, v.y, v.z, v.w};
    uint32_t r[4];
#pragma unroll
    for (int q = 0; q < 4; ++q) {
        float o01[2];
#pragma unroll
        for (int hh = 0; hh < 2; ++hh) {
            int c = c0 + 2 * q + hh;
            float s = stats1[(b * 128 + c) * 2 + 0];
            float qq = stats1[(b * 128 + c) * 2 + 1];
            float mu = s * invE;
            float rinv = rsqrtf(qq * invE - mu * mu + EPS);
            float y = bf2f(hh ? (ushort)(wds[q] >> 16) : (ushort)(wds[q] & 0xffff));
            float z = (y - mu) * rinv;
            o01[hh] = z > 0.f ? z : 0.f;
        }
        r[q] = pk2(o01[0], o01[1]);
    }
    reinterpret_cast<uint4*>(X1)[i] = make_uint4(r[0], r[1], r[2], r[3]);
}

// ---------- fused MFMA mesh conv (R22 structure: XCD-locality swizzle, 64-ch chunks,
// single LDS buffer) + NT_OUT: non-temporal output stores so the write stream does
// NOT evict the gather working set from the per-XCD L2 (gather set 2.3-3.5 MB +
// 2.3 MB write stream > 4 MB L2 without NT; the next reader of Out is streaming).
// MODE 0: plain gather; MODE 1: unpool(Y1)+concat(FD). OSPLIT: upconv 64-out halves.
template <int CIN, int MODE, bool STATS, bool OSPLIT, bool NT_OUT>
__global__ __launch_bounds__(512, 4) void conv_mfma(
    const ushort* __restrict__ Xs, const ushort* __restrict__ Aux,
    const int* __restrict__ gm, const int* __restrict__ parent,
    const float* __restrict__ pval,
    const ushort* __restrict__ Wq, const float* __restrict__ bias,
    ushort* __restrict__ Out, float* __restrict__ stats_out, int E) {
    static_assert(!(OSPLIT && STATS), "stats path not wired for OSPLIT");
    static_assert(CIN % 64 == 0, "64-channel chunks");
    constexpr int NCH = CIN / 64;         // 64-channel chunks (4 or 2)
    constexpr int NSTEP = CIN * 5 / 32;   // total K-steps (dense)
    constexpr int LDW = 328;              // 320 k' + 8 pad (bf16); 656B row
    constexpr int NET = OSPLIT ? 2 : 4;   // et-subtiles per wave
    __shared__ __align__(16) ushort Gs[64 * LDW];     // single buffer ~41 KB
    __shared__ int idx[320];
    __shared__ int par[MODE == 1 ? 320 : 1];
    __shared__ float pv[MODE == 1 ? 320 : 1];

    // XCD-locality decode (uniform across block; early return before any barrier)
    int g = blockIdx.x;
    int xcd = g & 7;
    int b = xcd >> 2;
    int within = (g >> 3) * 4 + (xcd & 3);
    int ebx, oh;
    if (OSPLIT) {
        if (within >= 142) return;        // 71 tiles x 2 out-halves
        ebx = within >> 1; oh = within & 1;
    } else {
        if (within >= 141) return;
        ebx = within; oh = 0;
    }
    int tid = threadIdx.x;
    int e0 = ebx * 64;

    if (tid < 320) {
        int e = tid / 5, k = tid % 5;
        int eg = e0 + e;
        int id = (eg < E) ? gm[((size_t)b * E + eg) * 5 + k] : 0;
        idx[tid] = id;
        if (MODE == 1) {
            par[tid] = parent[b * EOUT + id];
            pv[tid] = pval[b * EOUT + id];
        }
    }
    __syncthreads();

    int l = tid & 63, w = tid >> 6;       // 8 waves
    int lr = l & 15, lg = l >> 4;
    int og8 = OSPLIT ? (oh * 4 + (w & 3)) : w;    // o = og8*16 + lr
    int etb = OSPLIT ? ((w >> 2) * 2) : 0;        // et in [etb, etb+NET)
    int cg = tid & 7, eb = tid >> 3;      // stage: 8 ch-groups(8ch) x 64 edges
    bool evalid = (e0 + eb) < E;
    constexpr int XROW = (MODE == 0) ? CIN : 128;

    f32x4 acc[NET];
#pragma unroll
    for (int et = 0; et < NET; ++et) acc[et] = (f32x4)0.f;

    uint4 gv[5];
    auto loadG = [&](int chu) {
        int c0 = chu * 64 + cg * 8;
#pragma unroll
        for (int k = 0; k < 5; ++k) {
            gv[k] = make_uint4(0u, 0u, 0u, 0u);
            if (evalid) {
                int s5 = eb * 5 + k;
                const ushort* src;
                if (MODE == 1) {
                    if (chu < NCH / 2) src = Xs + ((size_t)b * EIN + par[s5]) * 128 + c0;
                    else src = Aux + ((size_t)b * EOUT + idx[s5]) * 128 + (c0 - 128);
                } else {
                    src = Xs + ((size_t)b * E + idx[s5]) * XROW + c0;
                }
                gv[k] = *reinterpret_cast<const uint4*>(src);
            }
        }
    };

    // stage: 8 channels/thread in two 4-ch halves -> 40 dense k'-slots at cg*80B
    auto stageG = [&](int chu) {
        float pvr[5];
        if (MODE == 1 && chu < NCH / 2) {
#pragma unroll
            for (int k = 0; k < 5; ++k) pvr[k] = pv[eb * 5 + k];
        }
#pragma unroll
        for (int h = 0; h < 2; ++h) {
            float fa[20];
#pragma unroll
            for (int j = 0; j < 4; ++j) {
                float f[5];
#pragma unroll
                for (int k = 0; k < 5; ++k) {
                    uint32_t word = (h == 0) ? ((j < 2) ? gv[k].x : gv[k].y)
                                             : ((j < 2) ? gv[k].z : gv[k].w);
                    ushort hv = (j & 1) ? (ushort)(word >> 16) : (ushort)(word & 0xffff);
                    f[k] = bf2f(hv);
                }
                if (MODE == 1 && chu < NCH / 2) {
#pragma unroll
                    for (int k = 0; k < 5; ++k) f[k] *= pvr[k];
                }
                fa[j * 5 + 0] = f[0];
                fa[j * 5 + 1] = f[1] + f[3];
                fa[j * 5 + 2] = f[2] + f[4];
                fa[j * 5 + 3] = fabsf(f[1] - f[3]);
                fa[j * 5 + 4] = fabsf(f[2] - f[4]);
            }
            uint32_t u[10];
#pragma unroll
            for (int q = 0; q < 10; ++q) u[q] = pk2(fa[2 * q], fa[2 * q + 1]);
            ushort* dst = Gs + eb * LDW + cg * 40 + h * 20;
#pragma unroll
            for (int q = 0; q < 5; ++q)
                *reinterpret_cast<uint2*>(dst + q * 4) = make_uint2(u[2 * q], u[2 * q + 1]);
        }
    };

    auto mfmaStep = [&](int chu) {
#pragma unroll
        for (int ks = 0; ks < 10; ++ks) {  // 10 K-steps of 32 k' per 64-ch chunk
            const ushort* wbase =
                Wq + ((size_t)(og8 * NSTEP + chu * 10 + ks) * 64 + l) * 8;
            bf16x8 bb = *reinterpret_cast<const bf16x8*>(wbase);
#pragma unroll
            for (int et = 0; et < NET; ++et) {
                bf16x8 a = *reinterpret_cast<const bf16x8*>(
                    Gs + ((etb + et) * 16 + lr) * LDW + ks * 32 + lg * 8);
                acc[et] = __builtin_amdgcn_mfma_f32_16x16x32_bf16(a, bb, acc[et], 0, 0, 0);
            }
        }
    };

    // single-buffer pipeline: stage(chu) -> barA -> issue loads(chu+1) ->
    // mfma(chu) -> barB.
    loadG(0);
    for (int chu = 0; chu < NCH; ++chu) {
        stageG(chu);
        __syncthreads();                       // barA
        if (chu + 1 < NCH) loadG(chu + 1);
        mfmaStep(chu);
        __syncthreads();                       // barB
    }

    // epilogue: D frag: col = lane&15 (=o), row = (lane>>4)*4 + r (=edge)
    {
        int o = og8 * 16 + lr;
        float bv = bias[o];
        float s = 0.f, q = 0.f;
#pragma unroll
        for (int et = 0; et < NET; ++et) {
#pragma unroll
            for (int r = 0; r < 4; ++r) {
                int e = e0 + (etb + et) * 16 + lg * 4 + r;
                if (e < E) {
                    float y = acc[et][r] + bv;
                    ushort* p = Out + ((size_t)b * E + e) * 128 + o;
                    if (NT_OUT) __builtin_nontemporal_store((ushort)bfr(y), p);
                    else *p = (ushort)bfr(y);
                    if (STATS) { s += y; q += y * y; }
                }
            }
        }
        if (STATS) {
            s += __shfl_xor(s, 16, 64); s += __shfl_xor(s, 32, 64);
            q += __shfl_xor(q, 16, 64); q += __shfl_xor(q, 32, 64);
            if (lg == 0) {
                atomicAdd(&stats_out[(b * 128 + o) * 2 + 0], s);
                atomicAdd(&stats_out[(b * 128 + o) * 2 + 1], q);
            }
        }
    }
}

// ---------- out[b][c][e] = relu( norm2(Y3) + X1 ), bf16 -> f32 ch-major (NT out)
__global__ void final_kernel(const ushort* __restrict__ Y3, const ushort* __restrict__ X1,
                             const float* __restrict__ stats2, float* __restrict__ out, int E) {
    __shared__ float tile[32 * 129];
    int b = blockIdx.y;
    int e0 = blockIdx.x * 32;
    int tid = threadIdx.x;
    float invE = 1.0f / (float)E;
#pragma unroll
    for (int i = 0; i < 16; ++i) {
        int idx = i * 256 + tid;
        int c = idx & 127, el = idx >> 7;
        int e = e0 + el;
        float v = 0.f;
        if (e < E) {
            float s2 = stats2[(b * 128 + c) * 2 + 0], q2 = stats2[(b * 128 + c) * 2 + 1];
            float mu2 = s2 * invE, var2 = q2 * invE - mu2 * mu2;
            float x1 = bf2f(X1[((size_t)b * E + e) * 128 + c]);
            float z = (bf2f(Y3[((size_t)b * E + e) * 128 + c]) - mu2) * rsqrtf(var2 + EPS);
            v = z + x1;
            v = v > 0.f ? v : 0.f;
        }
        tile[el * 129 + c] = v;
    }
    __syncthreads();
#pragma unroll
    for (int i = 0; i < 16; ++i) {
        int idx = i * 256 + tid;
        int el = idx & 31, c = idx >> 5;
        int e = e0 + el;
        if (e < E)
            __builtin_nontemporal_store(tile[el * 129 + c],
                                        &out[((size_t)b * 128 + c) * E + e]);
    }
}

extern "C" void kernel_launch(void* const* d_in, const int* in_sizes, int n_in,
                              void* d_out, int out_size, void* d_ws, size_t ws_size,
                              hipStream_t stream) {
    const float* from_up   = (const float*)d_in[0];
    const float* from_down = (const float*)d_in[1];
    const float* unroll    = (const float*)d_in[2];
    const float* W_up      = (const float*)d_in[3];
    const float* b_up      = (const float*)d_in[4];
    const float* W1        = (const float*)d_in[5];
    const float* b1        = (const float*)d_in[6];
    const float* W2        = (const float*)d_in[7];
    const float* b2        = (const float*)d_in[8];
    const int* gemm_up     = (const int*)d_in[9];
    const int* gemm_post   = (const int*)d_in[10];
    float* out = (float*)d_out;

    float* ws = (float*)d_ws;
    size_t off = 0;
    auto alloc = [&](size_t n) { float* p = ws + off; off += n; return p; };
    ushort* FU_bf = (ushort*)alloc((size_t)NB * EIN * 256 / 2);   // [B][EIN][256] bf16
    ushort* FD_bf = (ushort*)alloc((size_t)NB * EOUT * 128 / 2);  // [B][EOUT][128] bf16
    ushort* Wq_up = (ushort*)alloc(81920);                        // 128 x 1280 bf16 dense
    ushort* Wq_1  = (ushort*)alloc(81920);
    ushort* Wq_2  = (ushort*)alloc(40960);                        // 128 x 640
    ushort* Y1_bf = (ushort*)alloc((size_t)NB * EIN * 128 / 2);
    ushort* Y2_bf = (ushort*)alloc((size_t)NB * EOUT * 128 / 2);
    ushort* X1_bf = (ushort*)alloc((size_t)NB * EOUT * 128 / 2);
    ushort* Y3_bf = (ushort*)alloc((size_t)NB * EOUT * 128 / 2);
    float* stats  = alloc(1024);
    int*   parent = (int*)alloc(NB * EOUT);
    float* pval   = alloc(NB * EOUT);
    float* stats1 = stats, *stats2 = stats + 512;

    phase0_kernel<<<GUESS_B + FU_B + FD_B + WP_B + INIT_B, 256, 0, stream>>>(
        unroll, parent, pval, from_up, FU_bf, from_down, FD_bf,
        W_up, Wq_up, W1, Wq_1, W2, Wq_2, stats);

    // up conv: FU_bf -> Y1_bf (Y1 gathered by conv1 -> keep cached, no NT)
    conv_mfma<256, 0, false, true, false><<<288, 512, 0, stream>>>(
        FU_bf, nullptr, gemm_up, nullptr, nullptr, Wq_up, b_up, Y1_bf, nullptr, EIN);
    // conv1 (unpool+concat gather, stats1): Y2 NT-stored (next reader is streaming)
    conv_mfma<256, 1, true, false, true><<<288, 512, 0, stream>>>(
        Y1_bf, FD_bf, gemm_post, parent, pval, Wq_1, b1, Y2_bf, stats1, EOUT);
    // X1 = relu(norm1(Y2)) materialized once (X1 cached: conv2's gather target)
    norm_kernel<<<1125, 256, 0, stream>>>(Y2_bf, stats1, X1_bf);
    // conv2 (plain gather from X1, stats2): Y3 NT-stored (keeps X1 resident in L2)
    conv_mfma<128, 0, true, false, true><<<288, 512, 0, stream>>>(
        X1_bf, nullptr, gemm_post, nullptr, nullptr, Wq_2, b2, Y3_bf, stats2, EOUT);
    // final: norm2 + residual + relu + transpose to [B][C][E] f32 (NT out)
    final_kernel<<<dim3(282, NB), 256, 0, stream>>>(Y3_bf, X1_bf, stats2, out, EOUT);
}

// Round 24
// 94.527 us; speedup vs baseline: 1.0312x; 1.0312x over previous
//
#include <hip/hip_runtime.h>
#include <hip/hip_bf16.h>
#include <math.h>

#define NB 2
#define EIN 4500
#define EOUT 9000
#define EPS 1e-5f

typedef __attribute__((ext_vector_type(8))) short bf16x8;
typedef __attribute__((ext_vector_type(4))) float f32x4;

__device__ inline uint32_t bfr(float x) {
    uint32_t u = __float_as_uint(x);
    return (u + 0x7fffu + ((u >> 16) & 1u)) >> 16;
}
__device__ inline uint32_t pk2(float a, float b) {
    __hip_bfloat162 h = __float22bfloat162_rn(make_float2(a, b));   // v_cvt_pk_bf16_f32
    uint32_t u;
    __builtin_memcpy(&u, &h, 4);
    return u;
}
__device__ inline float bf2f(ushort u) { return __uint_as_float((uint32_t)u << 16); }

// ---------- W pack, DENSE k' = c*5 + f (R15 layout):
// Wq[((og8*NSTEP + st)*64 + lane)*8 + f8]: o = og8*16 + (lane&15),
// k' = st*32 + (lane>>4)*8 + f8, (c, feat) = (k'/5, k'%5).
__device__ inline void wpack_frag(const float* __restrict__ W, ushort* __restrict__ Wq,
                                  int i, int CIN) {
    int lane = i & 63; int t = i >> 6;
    int NSTEP = CIN * 5 / 32;
    int st = t % NSTEP, og = t / NSTEP;
    int o = og * 16 + (lane & 15);
    int k0 = st * 32 + (lane >> 4) * 8;
    uint32_t u[4];
#pragma unroll
    for (int q = 0; q < 4; ++q) {
        int ka = k0 + 2 * q, kb = ka + 1;
        float va = W[((size_t)o * CIN + ka / 5) * 5 + ka % 5];
        float vb = W[((size_t)o * CIN + kb / 5) * 5 + kb % 5];
        u[q] = pk2(va, vb);
    }
    *reinterpret_cast<uint4*>(Wq + (size_t)i * 8) = make_uint4(u[0], u[1], u[2], u[3]);
}

// ---------- tiled transpose f32 [R][C] -> bf16 [C][R] (one 32x32 tile per call)
__device__ inline void transpose_bf_body(float (*tile)[33], const float* __restrict__ in,
                                         ushort* __restrict__ out, int R, int C,
                                         int id, int nbx, int nby, int tid) {
    int bxt = id % nbx; int rest = id / nbx;
    int by = rest % nby; int b = rest / nby;
    int c0 = bxt * 32, r0 = by * 32;
    const float* inb = in + (size_t)b * R * C;
    ushort* outb = out + (size_t)b * C * R;
    int tx = tid & 31, ty = tid >> 5;   // 32 x 8
#pragma unroll
    for (int i = 0; i < 4; ++i) {
        int r = r0 + ty + i * 8, c = c0 + tx;
        if (r < R && c < C) tile[ty + i * 8][tx] = inb[(size_t)r * C + c];
    }
    __syncthreads();
#pragma unroll
    for (int i = 0; i < 4; ++i) {
        int c = c0 + ty + i * 8, r = r0 + tx;
        if (r < R && c < C) outb[(size_t)c * R + r] = (ushort)bfr(tile[tx][ty + i * 8]);
    }
}

// ---------- phase0: parent probe + transposes + wpack + stats-zero.
#define GUESS_B 71    // ceil(18000/256)
#define FU_B 2256     // 141 x 8 x 2
#define FD_B 2256     // 282 x 4 x 2
#define WP_B 200      // 51200 items / 256
#define INIT_B 1      // stats only (1024 floats)
__global__ __launch_bounds__(256) void phase0_kernel(
    const float* __restrict__ unroll, int* __restrict__ parent, float* __restrict__ pval,
    const float* __restrict__ from_up, ushort* __restrict__ FU,
    const float* __restrict__ from_down, ushort* __restrict__ FD,
    const float* __restrict__ W_up, ushort* __restrict__ Wq_up,
    const float* __restrict__ W1, ushort* __restrict__ Wq_1,
    const float* __restrict__ W2, ushort* __restrict__ Wq_2,
    float* __restrict__ stats) {
    __shared__ float tile[32][33];
    int bx = blockIdx.x, tid = threadIdx.x;
    if (bx < GUESS_B) {
        int i = bx * 256 + tid;          // i = b*EOUT + eo
        if (i < NB * EOUT) {
            int eo = i % EOUT;
            const float* mb = unroll + (size_t)(i / EOUT) * EIN * EOUT;
            int p = eo >> 1;
            float v = mb[(size_t)p * EOUT + eo];
            if (v == 0.f) {              // general 1-sparse fallback (never hit here)
                p = 0; v = 0.f;
                for (int ei = 0; ei < EIN; ++ei) {
                    float x = mb[(size_t)ei * EOUT + eo];
                    if (x != 0.f) { p = ei; v = x; break; }
                }
            }
            parent[i] = p;
            pval[i] = v;
        }
    } else if (bx < GUESS_B + FU_B) {
        transpose_bf_body(tile, from_up, FU, 256, EIN, bx - GUESS_B, 141, 8, tid);
    } else if (bx < GUESS_B + FU_B + FD_B) {
        transpose_bf_body(tile, from_down, FD, 128, EOUT, bx - (GUESS_B + FU_B), 282, 4, tid);
    } else if (bx < GUESS_B + FU_B + FD_B + WP_B) {
        int i = (bx - (GUESS_B + FU_B + FD_B)) * 256 + tid;
        if (i < 20480) wpack_frag(W_up, Wq_up, i, 256);              // 8og x 40st x 64
        else if (i < 40960) wpack_frag(W1, Wq_1, i - 20480, 256);
        else wpack_frag(W2, Wq_2, i - 40960, 128);                   // 8og x 20st x 64
    } else {
#pragma unroll
        for (int j = 0; j < 4; ++j) stats[j * 256 + tid] = 0.f;
    }
}

// ---------- X1 = relu(norm1(Y2)), materialized once (keeps conv2 stage path lean).
__global__ void norm_kernel(const ushort* __restrict__ Y2, const float* __restrict__ stats1,
                            ushort* __restrict__ X1) {
    int i = blockIdx.x * 256 + threadIdx.x;      // uint4 index
    if (i >= NB * EOUT * 128 / 8) return;
    int c0 = (i * 8) & 127;
    int b = (i * 8) / (EOUT * 128);
    float invE = 1.0f / (float)EOUT;
    uint4 v = reinterpret_cast<const uint4*>(Y2)[i];
    uint32_t wds[4] = {v.x, v.y, v.z, v.w};
    uint32_t r[4];
#pragma unroll
    for (int q = 0; q < 4; ++q) {
        float o01[2];
#pragma unroll
        for (int hh = 0; hh < 2; ++hh) {
            int c = c0 + 2 * q + hh;
            float s = stats1[(b * 128 + c) * 2 + 0];
            float qq = stats1[(b * 128 + c) * 2 + 1];
            float mu = s * invE;
            float rinv = rsqrtf(qq * invE - mu * mu + EPS);
            float y = bf2f(hh ? (ushort)(wds[q] >> 16) : (ushort)(wds[q] & 0xffff));
            float z = (y - mu) * rinv;
            o01[hh] = z > 0.f ? z : 0.f;
        }
        r[q] = pk2(o01[0], o01[1]);
    }
    reinterpret_cast<uint4*>(X1)[i] = make_uint4(r[0], r[1], r[2], r[3]);
}

// ---------- fused MFMA mesh conv (R22 final structure): XCD-locality swizzle
// (batch 0 -> XCDs 0-3, batch 1 -> XCDs 4-7; per-XCD L2 holds one batch's gather
// set), 64 edges x 128 outs, 8 waves, DENSE K', 64-ch chunks, single LDS buffer,
// stage -> barA -> issue-next-loads -> mfma -> barB. OSPLIT: upconv 64-out halves.
// MODE 0: plain gather; MODE 1: unpool(Y1)+concat(FD).
template <int CIN, int MODE, bool STATS, bool OSPLIT = false>
__global__ __launch_bounds__(512, 4) void conv_mfma(
    const ushort* __restrict__ Xs, const ushort* __restrict__ Aux,
    const int* __restrict__ gm, const int* __restrict__ parent,
    const float* __restrict__ pval,
    const ushort* __restrict__ Wq, const float* __restrict__ bias,
    ushort* __restrict__ Out, float* __restrict__ stats_out, int E) {
    static_assert(!(OSPLIT && STATS), "stats path not wired for OSPLIT");
    static_assert(CIN % 64 == 0, "64-channel chunks");
    constexpr int NCH = CIN / 64;         // 64-channel chunks (4 or 2)
    constexpr int NSTEP = CIN * 5 / 32;   // total K-steps (dense)
    constexpr int LDW = 328;              // 320 k' + 8 pad (bf16); 656B row
    constexpr int NET = OSPLIT ? 2 : 4;   // et-subtiles per wave
    __shared__ __align__(16) ushort Gs[64 * LDW];     // single buffer ~41 KB
    __shared__ int idx[320];
    __shared__ int par[MODE == 1 ? 320 : 1];
    __shared__ float pv[MODE == 1 ? 320 : 1];

    // XCD-locality decode (uniform across block; early return before any barrier)
    int g = blockIdx.x;
    int xcd = g & 7;
    int b = xcd >> 2;
    int within = (g >> 3) * 4 + (xcd & 3);
    int ebx, oh;
    if (OSPLIT) {
        if (within >= 142) return;        // 71 tiles x 2 out-halves
        ebx = within >> 1; oh = within & 1;
    } else {
        if (within >= 141) return;
        ebx = within; oh = 0;
    }
    int tid = threadIdx.x;
    int e0 = ebx * 64;

    if (tid < 320) {
        int e = tid / 5, k = tid % 5;
        int eg = e0 + e;
        int id = (eg < E) ? gm[((size_t)b * E + eg) * 5 + k] : 0;
        idx[tid] = id;
        if (MODE == 1) {
            par[tid] = parent[b * EOUT + id];
            pv[tid] = pval[b * EOUT + id];
        }
    }
    __syncthreads();

    int l = tid & 63, w = tid >> 6;       // 8 waves
    int lr = l & 15, lg = l >> 4;
    int og8 = OSPLIT ? (oh * 4 + (w & 3)) : w;    // o = og8*16 + lr
    int etb = OSPLIT ? ((w >> 2) * 2) : 0;        // et in [etb, etb+NET)
    int cg = tid & 7, eb = tid >> 3;      // stage: 8 ch-groups(8ch) x 64 edges
    bool evalid = (e0 + eb) < E;
    constexpr int XROW = (MODE == 0) ? CIN : 128;

    f32x4 acc[NET];
#pragma unroll
    for (int et = 0; et < NET; ++et) acc[et] = (f32x4)0.f;

    uint4 gv[5];
    auto loadG = [&](int chu) {
        int c0 = chu * 64 + cg * 8;
#pragma unroll
        for (int k = 0; k < 5; ++k) {
            gv[k] = make_uint4(0u, 0u, 0u, 0u);
            if (evalid) {
                int s5 = eb * 5 + k;
                const ushort* src;
                if (MODE == 1) {
                    if (chu < NCH / 2) src = Xs + ((size_t)b * EIN + par[s5]) * 128 + c0;
                    else src = Aux + ((size_t)b * EOUT + idx[s5]) * 128 + (c0 - 128);
                } else {
                    src = Xs + ((size_t)b * E + idx[s5]) * XROW + c0;
                }
                gv[k] = *reinterpret_cast<const uint4*>(src);
            }
        }
    };

    // stage: 8 channels/thread in two 4-ch halves -> 40 dense k'-slots at cg*80B
    auto stageG = [&](int chu) {
        float pvr[5];
        if (MODE == 1 && chu < NCH / 2) {
#pragma unroll
            for (int k = 0; k < 5; ++k) pvr[k] = pv[eb * 5 + k];
        }
#pragma unroll
        for (int h = 0; h < 2; ++h) {
            float fa[20];
#pragma unroll
            for (int j = 0; j < 4; ++j) {
                float f[5];
#pragma unroll
                for (int k = 0; k < 5; ++k) {
                    uint32_t word = (h == 0) ? ((j < 2) ? gv[k].x : gv[k].y)
                                             : ((j < 2) ? gv[k].z : gv[k].w);
                    ushort hv = (j & 1) ? (ushort)(word >> 16) : (ushort)(word & 0xffff);
                    f[k] = bf2f(hv);
                }
                if (MODE == 1 && chu < NCH / 2) {
#pragma unroll
                    for (int k = 0; k < 5; ++k) f[k] *= pvr[k];
                }
                fa[j * 5 + 0] = f[0];
                fa[j * 5 + 1] = f[1] + f[3];
                fa[j * 5 + 2] = f[2] + f[4];
                fa[j * 5 + 3] = fabsf(f[1] - f[3]);
                fa[j * 5 + 4] = fabsf(f[2] - f[4]);
            }
            uint32_t u[10];
#pragma unroll
            for (int q = 0; q < 10; ++q) u[q] = pk2(fa[2 * q], fa[2 * q + 1]);
            ushort* dst = Gs + eb * LDW + cg * 40 + h * 20;
#pragma unroll
            for (int q = 0; q < 5; ++q)
                *reinterpret_cast<uint2*>(dst + q * 4) = make_uint2(u[2 * q], u[2 * q + 1]);
        }
    };

    auto mfmaStep = [&](int chu) {
#pragma unroll
        for (int ks = 0; ks < 10; ++ks) {  // 10 K-steps of 32 k' per 64-ch chunk
            const ushort* wbase =
                Wq + ((size_t)(og8 * NSTEP + chu * 10 + ks) * 64 + l) * 8;
            bf16x8 bb = *reinterpret_cast<const bf16x8*>(wbase);
#pragma unroll
            for (int et = 0; et < NET; ++et) {
                bf16x8 a = *reinterpret_cast<const bf16x8*>(
                    Gs + ((etb + et) * 16 + lr) * LDW + ks * 32 + lg * 8);
                acc[et] = __builtin_amdgcn_mfma_f32_16x16x32_bf16(a, bb, acc[et], 0, 0, 0);
            }
        }
    };

    // single-buffer pipeline: stage(chu) -> barA -> issue loads(chu+1) ->
    // mfma(chu) -> barB.
    loadG(0);
    for (int chu = 0; chu < NCH; ++chu) {
        stageG(chu);
        __syncthreads();                       // barA
        if (chu + 1 < NCH) loadG(chu + 1);
        mfmaStep(chu);
        __syncthreads();                       // barB
    }

    // epilogue: D frag: col = lane&15 (=o), row = (lane>>4)*4 + r (=edge)
    {
        int o = og8 * 16 + lr;
        float bv = bias[o];
        float s = 0.f, q = 0.f;
#pragma unroll
        for (int et = 0; et < NET; ++et) {
#pragma unroll
            for (int r = 0; r < 4; ++r) {
                int e = e0 + (etb + et) * 16 + lg * 4 + r;
                if (e < E) {
                    float y = acc[et][r] + bv;
                    Out[((size_t)b * E + e) * 128 + o] = (ushort)bfr(y);
                    if (STATS) { s += y; q += y * y; }
                }
            }
        }
        if (STATS) {
            s += __shfl_xor(s, 16, 64); s += __shfl_xor(s, 32, 64);
            q += __shfl_xor(q, 16, 64); q += __shfl_xor(q, 32, 64);
            if (lg == 0) {
                atomicAdd(&stats_out[(b * 128 + o) * 2 + 0], s);
                atomicAdd(&stats_out[(b * 128 + o) * 2 + 1], q);
            }
        }
    }
}

// ---------- out[b][c][e] = relu( norm2(Y3) + X1 ), bf16 -> f32 ch-major
__global__ void final_kernel(const ushort* __restrict__ Y3, const ushort* __restrict__ X1,
                             const float* __restrict__ stats2, float* __restrict__ out, int E) {
    __shared__ float tile[32 * 129];
    int b = blockIdx.y;
    int e0 = blockIdx.x * 32;
    int tid = threadIdx.x;
    float invE = 1.0f / (float)E;
#pragma unroll
    for (int i = 0; i < 16; ++i) {
        int idx = i * 256 + tid;
        int c = idx & 127, el = idx >> 7;
        int e = e0 + el;
        float v = 0.f;
        if (e < E) {
            float s2 = stats2[(b * 128 + c) * 2 + 0], q2 = stats2[(b * 128 + c) * 2 + 1];
            float mu2 = s2 * invE, var2 = q2 * invE - mu2 * mu2;
            float x1 = bf2f(X1[((size_t)b * E + e) * 128 + c]);
            float z = (bf2f(Y3[((size_t)b * E + e) * 128 + c]) - mu2) * rsqrtf(var2 + EPS);
            v = z + x1;
            v = v > 0.f ? v : 0.f;
        }
        tile[el * 129 + c] = v;
    }
    __syncthreads();
#pragma unroll
    for (int i = 0; i < 16; ++i) {
        int idx = i * 256 + tid;
        int el = idx & 31, c = idx >> 5;
        int e = e0 + el;
        if (e < E) out[((size_t)b * 128 + c) * E + e] = tile[el * 129 + c];
    }
}

extern "C" void kernel_launch(void* const* d_in, const int* in_sizes, int n_in,
                              void* d_out, int out_size, void* d_ws, size_t ws_size,
                              hipStream_t stream) {
    const float* from_up   = (const float*)d_in[0];
    const float* from_down = (const float*)d_in[1];
    const float* unroll    = (const float*)d_in[2];
    const float* W_up      = (const float*)d_in[3];
    const float* b_up      = (const float*)d_in[4];
    const float* W1        = (const float*)d_in[5];
    const float* b1        = (const float*)d_in[6];
    const float* W2        = (const float*)d_in[7];
    const float* b2        = (const float*)d_in[8];
    const int* gemm_up     = (const int*)d_in[9];
    const int* gemm_post   = (const int*)d_in[10];
    float* out = (float*)d_out;

    float* ws = (float*)d_ws;
    size_t off = 0;
    auto alloc = [&](size_t n) { float* p = ws + off; off += n; return p; };
    ushort* FU_bf = (ushort*)alloc((size_t)NB * EIN * 256 / 2);   // [B][EIN][256] bf16
    ushort* FD_bf = (ushort*)alloc((size_t)NB * EOUT * 128 / 2);  // [B][EOUT][128] bf16
    ushort* Wq_up = (ushort*)alloc(81920);                        // 128 x 1280 bf16 dense
    ushort* Wq_1  = (ushort*)alloc(81920);
    ushort* Wq_2  = (ushort*)alloc(40960);                        // 128 x 640
    ushort* Y1_bf = (ushort*)alloc((size_t)NB * EIN * 128 / 2);
    ushort* Y2_bf = (ushort*)alloc((size_t)NB * EOUT * 128 / 2);
    ushort* X1_bf = (ushort*)alloc((size_t)NB * EOUT * 128 / 2);
    ushort* Y3_bf = (ushort*)alloc((size_t)NB * EOUT * 128 / 2);
    float* stats  = alloc(1024);
    int*   parent = (int*)alloc(NB * EOUT);
    float* pval   = alloc(NB * EOUT);
    float* stats1 = stats, *stats2 = stats + 512;

    phase0_kernel<<<GUESS_B + FU_B + FD_B + WP_B + INIT_B, 256, 0, stream>>>(
        unroll, parent, pval, from_up, FU_bf, from_down, FD_bf,
        W_up, Wq_up, W1, Wq_1, W2, Wq_2, stats);

    // up conv: FU_bf -> Y1_bf  (XCD-swizzled; 288 blocks)
    conv_mfma<256, 0, false, true><<<288, 512, 0, stream>>>(
        FU_bf, nullptr, gemm_up, nullptr, nullptr, Wq_up, b_up, Y1_bf, nullptr, EIN);
    // conv1 (fused unpool+concat gather, fused stats1): -> Y2_bf
    conv_mfma<256, 1, true><<<288, 512, 0, stream>>>(
        Y1_bf, FD_bf, gemm_post, parent, pval, Wq_1, b1, Y2_bf, stats1, EOUT);
    // X1 = relu(norm1(Y2)) materialized once
    norm_kernel<<<1125, 256, 0, stream>>>(Y2_bf, stats1, X1_bf);
    // conv2 (plain gather from X1, fused stats2): -> Y3_bf
    conv_mfma<128, 0, true><<<288, 512, 0, stream>>>(
        X1_bf, nullptr, gemm_post, nullptr, nullptr, Wq_2, b2, Y3_bf, stats2, EOUT);
    // final: norm2 + residual + relu + transpose to [B][C][E] f32
    final_kernel<<<dim3(282, NB), 256, 0, stream>>>(Y3_bf, X1_bf, stats2, out, EOUT);
}